// Round 1
// baseline (773.018 us; speedup 1.0000x reference)
//
#include <hip/hip_runtime.h>
#include <hip/hip_bf16.h>

#define B_  8
#define C_  128
#define HW  16384            // 128*128
#define OC  384              // 3*C

// ---------------- workspace layout (float offsets) ----------------
// qkv1 : [8][384][16384]  pre-dwconv qkv (1x1 conv output)         201.3 MB
// wqkvT: [128][384]       w_qkv transposed (k-major for GEMM)
// G    : [8][8][16][16]   raw gram q.k (atomic accum)
// nqk  : [8][256]         sum-of-squares of dw'd q,k rows (atomic)
// attn : [8][8][16][16]   softmax'd attention
// CtB  : [8][128][128]    k-major combined (Wproj @ blockdiag(attn))
// V-gated lives in d_out (dead until final GEMM; per-block column tiles
// are read fully before being overwritten).
static const long OFF_QKV1 = 0;
static const long OFF_WT   = OFF_QKV1 + (long)B_ * OC * HW;   // 50331648
static const long OFF_G    = OFF_WT   + 128L * OC;            // +49152
static const long OFF_NQK  = OFF_G    + 8L * 8 * 16 * 16;     // +16384
static const long OFF_ATTN = OFF_NQK  + 8L * 256;             // +2048
static const long OFF_CTB  = OFF_ATTN + 8L * 8 * 16 * 16;     // +16384

// -------------------------------------------------------------------
__global__ void transpose_w(const float* __restrict__ w, float* __restrict__ wt)
{
    int e = blockIdx.x * 256 + threadIdx.x;   // e < 49152 exactly
    int c = e / 384, o = e % 384;
    wt[e] = w[o * 128 + c];                   // wt[c][o] = w[o][c]
}

// C[b][m][n] = sum_k At[b][k][m] * B[b][k][n]   (K=128, N=16384)
// At is k-major with row stride M. B/C NOT restrict: final call aliases them.
__global__ __launch_bounds__(256) void gemm128(
    const float* __restrict__ At, long atStrideB, int M,
    const float* Bm, float* Cm)
{
    const int b  = blockIdx.z;
    const int m0 = blockIdx.y * 128;
    const int n0 = blockIdx.x * 128;
    const float* at = At + (long)b * atStrideB;
    const float* Bb = Bm + (long)b * C_ * (long)HW;
    float*       Cb = Cm + (long)b * M  * (long)HW;

    __shared__ float As[32][128];
    __shared__ float Bs[32][128];

    const int tid = threadIdx.x;
    const int tx = tid & 15;
    const int ty = tid >> 4;

    float acc[8][8];
#pragma unroll
    for (int i = 0; i < 8; ++i)
#pragma unroll
        for (int j = 0; j < 8; ++j) acc[i][j] = 0.f;

#pragma unroll 1
    for (int k0 = 0; k0 < 128; k0 += 32) {
#pragma unroll
        for (int i = 0; i < 4; ++i) {
            int e  = tid + i * 256;          // float4 units, 0..1023
            int kk = e >> 5;                 // 0..31
            int m4 = (e & 31) << 2;          // 0..124 step 4
            *(float4*)&As[kk][m4] = *(const float4*)&at[(long)(k0 + kk) * M + m0 + m4];
            *(float4*)&Bs[kk][m4] = *(const float4*)&Bb[(long)(k0 + kk) * HW + n0 + m4];
        }
        __syncthreads();
#pragma unroll 8
        for (int kk = 0; kk < 32; ++kk) {
            float4 a0 = *(const float4*)&As[kk][ty * 4];
            float4 a1 = *(const float4*)&As[kk][64 + ty * 4];
            float4 b0 = *(const float4*)&Bs[kk][tx * 4];
            float4 b1 = *(const float4*)&Bs[kk][64 + tx * 4];
            float ar[8] = {a0.x, a0.y, a0.z, a0.w, a1.x, a1.y, a1.z, a1.w};
            float br[8] = {b0.x, b0.y, b0.z, b0.w, b1.x, b1.y, b1.z, b1.w};
#pragma unroll
            for (int i = 0; i < 8; ++i)
#pragma unroll
                for (int j = 0; j < 8; ++j)
                    acc[i][j] = fmaf(ar[i], br[j], acc[i][j]);
        }
        __syncthreads();
    }

#pragma unroll
    for (int ih = 0; ih < 2; ++ih)
#pragma unroll
        for (int i = 0; i < 4; ++i) {
            int m = m0 + ih * 64 + ty * 4 + i;
            float4 v0 = make_float4(acc[ih*4+i][0], acc[ih*4+i][1], acc[ih*4+i][2], acc[ih*4+i][3]);
            float4 v1 = make_float4(acc[ih*4+i][4], acc[ih*4+i][5], acc[ih*4+i][6], acc[ih*4+i][7]);
            *(float4*)&Cb[(long)m * HW + n0 + tx * 4]      = v0;
            *(float4*)&Cb[(long)m * HW + n0 + 64 + tx * 4] = v1;
        }
}

// Depthwise 3x3 (SAME, zero pad). ch<256 (q,k): accumulate row sum-of-squares
// into nqk (atomic). ch>=256 (v): gate with illu and store to Vg (=d_out).
__global__ __launch_bounds__(256) void dw_norm_gate(
    const float* __restrict__ qkv1, const float* __restrict__ wdw,
    const float* __restrict__ illu, float* __restrict__ Vg,
    float* __restrict__ nqk)
{
    const int b = blockIdx.z, ch = blockIdx.y;
    const int y0 = blockIdx.x * 8;
    const int tid = threadIdx.x;
    __shared__ float lds[10][130];
    __shared__ float wsum[4];
    const float* in = qkv1 + ((long)b * OC + ch) * HW;

    float wv[9];
#pragma unroll
    for (int j = 0; j < 9; ++j) wv[j] = wdw[ch * 9 + j];

#pragma unroll
    for (int i = 0; i < 5; ++i) {
        int e = tid + i * 256;              // 0..1279 = 10 rows * 128
        int row = e >> 7, x = e & 127;
        int yy = y0 + row - 1;
        lds[row][x + 1] = (yy >= 0 && yy < 128) ? in[yy * 128 + x] : 0.f;
    }
    if (tid < 10) lds[tid][0] = 0.f;
    else if (tid < 20) lds[tid - 10][129] = 0.f;
    __syncthreads();

    const int x = tid & 127;
    const int rbase = (tid >> 7) * 4;       // 2 thread-rows * 4 outputs
    float o[4];
#pragma unroll
    for (int rr = 0; rr < 4; ++rr) {
        int ry = rbase + rr;
        float a = 0.f;
#pragma unroll
        for (int ky = 0; ky < 3; ++ky)
#pragma unroll
            for (int kx = 0; kx < 3; ++kx)
                a = fmaf(wv[ky * 3 + kx], lds[ry + ky][x + kx], a);
        o[rr] = a;
    }

    if (ch >= 256) {
        const int c = ch - 256;
        const float* ib = illu + ((long)b * C_ + c) * HW + y0 * 128;
        float*       ob = Vg   + ((long)b * C_ + c) * HW + y0 * 128;
#pragma unroll
        for (int rr = 0; rr < 4; ++rr) {
            int ry = rbase + rr;
            ob[ry * 128 + x] = o[rr] * ib[ry * 128 + x];
        }
    } else {
        float s = o[0]*o[0] + o[1]*o[1] + o[2]*o[2] + o[3]*o[3];
#pragma unroll
        for (int off = 32; off > 0; off >>= 1) s += __shfl_down(s, off);
        if ((tid & 63) == 0) wsum[tid >> 6] = s;
        __syncthreads();
        if (tid == 0) atomicAdd(&nqk[b * 256 + ch], wsum[0] + wsum[1] + wsum[2] + wsum[3]);
    }
}

// Gram: G[b][hd][c][d] += sum_n dwq[c][n] * dwk[d][n], dw recomputed on the fly.
// Thread = (jp 0..15, cq 0..3, dq 0..3) with 4x4 register outer product.
__global__ __launch_bounds__(256) void gram_kernel(
    const float* __restrict__ qkv1, const float* __restrict__ wdw,
    float* __restrict__ G)
{
    const int chunk = blockIdx.x;            // 16 chunks of 8 rows
    const int hd = blockIdx.y, b = blockIdx.z;
    const int tid = threadIdx.x;
    __shared__ float sq[16][132], sk[16][132];
    __shared__ float wq[144], wk[144];
    __shared__ float red[16][16][16];

    if (tid < 144)  wq[tid] = wdw[(hd * 16 + tid / 9) * 9 + tid % 9];
    if (tid >= 112) { int t2 = tid - 112; wk[t2] = wdw[(128 + hd * 16 + t2 / 9) * 9 + t2 % 9]; }

    const float* qb = qkv1 + ((long)b * OC + hd * 16) * HW;
    const float* kb = qkv1 + ((long)b * OC + 128 + hd * 16) * HW;

    const int jp = tid & 15, cq = (tid >> 4) & 3, dq = tid >> 6;
    float acc[4][4];
#pragma unroll
    for (int u = 0; u < 4; ++u)
#pragma unroll
        for (int v = 0; v < 4; ++v) acc[u][v] = 0.f;

    __syncthreads();
#pragma unroll 1
    for (int t = 0; t < 8; ++t) {
        const int y = chunk * 8 + t;
        // stage dw'd q,k rows for this image row: 2 ops * 16 ch * 128 x
#pragma unroll 1
        for (int i = 0; i < 16; ++i) {
            int e = tid + i * 256;
            int op = e >> 11, c = (e >> 7) & 15, x = e & 127;
            const float* in = (op ? kb : qb) + (long)c * HW;
            const float* wv = (op ? wk : wq) + c * 9;
            float a = 0.f;
#pragma unroll
            for (int ky = 0; ky < 3; ++ky) {
                int yy = y + ky - 1;
                if (yy < 0 || yy > 127) continue;
#pragma unroll
                for (int kx = 0; kx < 3; ++kx) {
                    int xx = x + kx - 1;
                    if (xx < 0 || xx > 127) continue;
                    a = fmaf(wv[ky * 3 + kx], in[yy * 128 + xx], a);
                }
            }
            if (op) sk[c][x] = a; else sq[c][x] = a;
        }
        __syncthreads();
#pragma unroll
        for (int it = 0; it < 2; ++it) {
            int j4 = (jp + 16 * it) * 4;
            float4 q4[4], k4[4];
#pragma unroll
            for (int u = 0; u < 4; ++u) q4[u] = *(const float4*)&sq[cq * 4 + u][j4];
#pragma unroll
            for (int v = 0; v < 4; ++v) k4[v] = *(const float4*)&sk[dq * 4 + v][j4];
#pragma unroll
            for (int u = 0; u < 4; ++u)
#pragma unroll
                for (int v = 0; v < 4; ++v)
                    acc[u][v] += q4[u].x * k4[v].x + q4[u].y * k4[v].y
                               + q4[u].z * k4[v].z + q4[u].w * k4[v].w;
        }
        __syncthreads();
    }
    // reduce 16 j-phases
#pragma unroll
    for (int u = 0; u < 4; ++u)
#pragma unroll
        for (int v = 0; v < 4; ++v) red[jp][cq * 4 + u][dq * 4 + v] = acc[u][v];
    __syncthreads();
    const int c = tid >> 4, d = tid & 15;
    float g = 0.f;
#pragma unroll
    for (int p = 0; p < 16; ++p) g += red[p][c][d];
    atomicAdd(&G[(((long)b * 8 + hd) * 16 + c) * 16 + d], g);
}

// attn = softmax( G / (max(|q_c|,eps)*max(|k_d|,eps)) * temp[hd] ) over d
__global__ void softmax_attn(const float* __restrict__ G, const float* __restrict__ nqk,
                             const float* __restrict__ temp, float* __restrict__ attn)
{
    const int hd = blockIdx.x, b = blockIdx.y;
    const int r = threadIdx.x;
    if (r >= 16) return;
    const float tv = temp[hd];
    const float* g = G + ((long)(b * 8 + hd) * 16 + r) * 16;
    float mq = fmaxf(sqrtf(nqk[b * 256 + hd * 16 + r]), 1e-12f);
    float L[16];
    float mx = -1e30f;
#pragma unroll
    for (int d = 0; d < 16; ++d) {
        float mk = fmaxf(sqrtf(nqk[b * 256 + 128 + hd * 16 + d]), 1e-12f);
        L[d] = g[d] * tv / (mq * mk);
        mx = fmaxf(mx, L[d]);
    }
    float s = 0.f;
#pragma unroll
    for (int d = 0; d < 16; ++d) { L[d] = expf(L[d] - mx); s += L[d]; }
    float inv = 1.f / s;
    float* arow = attn + ((long)(b * 8 + hd) * 16 + r) * 16;
#pragma unroll
    for (int d = 0; d < 16; ++d) arow[d] = L[d] * inv;
}

// CtB[b][D][o] = sum_c wproj[o][hd(D)*16+c] * attn[b][hd(D)][c][d(D)]  (k-major)
__global__ __launch_bounds__(256) void compose_kernel(
    const float* __restrict__ wproj, const float* __restrict__ attn,
    float* __restrict__ CtB)
{
    const int b = blockIdx.x, tid = threadIdx.x;
#pragma unroll 1
    for (int e = tid; e < 16384; e += 256) {
        const int D = e >> 7, o = e & 127;
        const int hd = D >> 4, d = D & 15;
        const float* ar = attn + (long)(b * 8 + hd) * 256 + d;   // + c*16
        const float* wr = wproj + o * 128 + hd * 16;
        float s = 0.f;
#pragma unroll
        for (int c2 = 0; c2 < 16; ++c2) s = fmaf(wr[c2], ar[c2 * 16], s);
        CtB[((long)b * 128 + D) * 128 + o] = s;
    }
}

extern "C" void kernel_launch(void* const* d_in, const int* in_sizes, int n_in,
                              void* d_out, int out_size, void* d_ws, size_t ws_size,
                              hipStream_t stream)
{
    const float* x     = (const float*)d_in[0];
    const float* illu  = (const float*)d_in[1];
    const float* wqkv  = (const float*)d_in[2];
    const float* wdw   = (const float*)d_in[3];
    const float* wproj = (const float*)d_in[4];
    const float* temp  = (const float*)d_in[5];
    float* out = (float*)d_out;
    float* ws  = (float*)d_ws;

    float* qkv1 = ws + OFF_QKV1;
    float* wT   = ws + OFF_WT;
    float* G    = ws + OFF_G;
    float* nqk  = ws + OFF_NQK;
    float* attn = ws + OFF_ATTN;
    float* CtB  = ws + OFF_CTB;

    hipLaunchKernelGGL(transpose_w, dim3(192), dim3(256), 0, stream, wqkv, wT);
    hipMemsetAsync(G, 0, (16384 + 2048) * sizeof(float), stream);  // G + nqk
    // K1: qkv = Wqkv @ x   -> ws.qkv1
    hipLaunchKernelGGL(gemm128, dim3(128, 3, 8), dim3(256), 0, stream,
                       wT, 0L, 384, x, qkv1);
    // K2: dwconv; q,k -> norms (atomic); v -> gated into d_out
    hipLaunchKernelGGL(dw_norm_gate, dim3(16, 384, 8), dim3(256), 0, stream,
                       qkv1, wdw, illu, out, nqk);
    // K3: gram (dw recomputed on the fly)
    hipLaunchKernelGGL(gram_kernel, dim3(16, 8, 8), dim3(256), 0, stream,
                       qkv1, wdw, G);
    // K4: normalize + softmax
    hipLaunchKernelGGL(softmax_attn, dim3(8, 8), dim3(64), 0, stream,
                       G, nqk, temp, attn);
    // K5: CtB = Wproj @ blockdiag(attn), k-major
    hipLaunchKernelGGL(compose_kernel, dim3(8), dim3(256), 0, stream,
                       wproj, attn, CtB);
    // K6: out = CtB @ Vgated  (B and C alias d_out; per-block column tiles
    // are fully read before the epilogue writes them)
    hipLaunchKernelGGL(gemm128, dim3(128, 1, 8), dim3(256), 0, stream,
                       CtB, 16384L, 128, out, out);
}

// Round 3
// 347.802 us; speedup vs baseline: 2.2226x; 2.2226x over previous
//
#include <hip/hip_runtime.h>
#include <hip/hip_bf16.h>

// ---------------- types ----------------
typedef __attribute__((ext_vector_type(8))) short bf16x8;   // 8 bf16 (4 VGPRs)
typedef __attribute__((ext_vector_type(4))) float f32x4;    // MFMA accum

__device__ __forceinline__ unsigned short f2b(float f) {
    unsigned int u = __builtin_bit_cast(unsigned int, f);
    u += 0x7FFFu + ((u >> 16) & 1u);          // RNE
    return (unsigned short)(u >> 16);
}
__device__ __forceinline__ float b2f(unsigned short h) {
    unsigned int u = ((unsigned int)h) << 16;
    return __builtin_bit_cast(float, u);
}

// ---------------- workspace layout (byte offsets) ----------------
// qkv1 bf16 [8][384][16384]                100,663,296 B
// dwqk bf16 [8][256][16384]                 67,108,864 B   (xT bf16 [8][16384][128] aliases its first 33.5MB; xT dead before dwqk written)
// VgT  bf16 [8][16384][128]                 33,554,432 B
// wbf  bf16 [384][128]                          98,304 B
// G    f32  [8][8][16][16]                      65,536 B
// nqk  f32  [8][256]                             8,192 B
// attn f32  [8][8][16][16]                      65,536 B
// CtBo bf16 [8][128][128]                      262,144 B
// total 201,826,304 B  (< proven 202.19 MB budget)
#define OFFB_QKV1 0L
#define OFFB_DWQK 100663296L
#define OFFB_VGT  167772160L
#define OFFB_WBF  201326592L
#define OFFB_G    201424896L
#define OFFB_NQK  201490432L
#define OFFB_ATTN 201498624L
#define OFFB_CTB  201564160L

// ---------------- prep: w_qkv fp32 -> bf16 (same [o][c] layout, k-contig) ---
__global__ __launch_bounds__(256) void prep_w(const float* __restrict__ w,
                                              unsigned short* __restrict__ wbf)
{
    int e = blockIdx.x * 256 + threadIdx.x;           // < 12288
    float4 v = *(const float4*)&w[e * 4];
    unsigned int p0 = (unsigned int)f2b(v.x) | ((unsigned int)f2b(v.y) << 16);
    unsigned int p1 = (unsigned int)f2b(v.z) | ((unsigned int)f2b(v.w) << 16);
    *(uint2*)&wbf[e * 4] = make_uint2(p0, p1);
}

// ------------- transpose+convert: fp32 [b][128][16384] -> bf16 [b][16384][128]
__global__ __launch_bounds__(256) void transpose_cb(const float* __restrict__ in,
                                                    unsigned short* __restrict__ out)
{
    const int b  = blockIdx.z;
    const int c0 = blockIdx.y * 32;
    const int n0 = blockIdx.x * 64;
    __shared__ float s[32][65];
    const int tid = threadIdx.x;
    const float* ib = in + ((long)b * 128 + c0) * 16384 + n0;
#pragma unroll
    for (int i = 0; i < 2; ++i) {
        int e = tid + i * 256;                        // 0..511 float4 units
        int c = e >> 4, n4 = (e & 15) * 4;
        *(float4*)&s[c][n4] = *(const float4*)&ib[(long)c * 16384 + n4];
    }
    __syncthreads();
    const int n = tid >> 2, cg = (tid & 3) * 8;
    unsigned int p[4];
#pragma unroll
    for (int j = 0; j < 4; ++j)
        p[j] = (unsigned int)f2b(s[cg + 2*j][n]) | ((unsigned int)f2b(s[cg + 2*j + 1][n]) << 16);
    *(uint4*)&out[((long)b * 16384 + n0 + n) * 128 + c0 + cg] = make_uint4(p[0], p[1], p[2], p[3]);
}

// ---------------- MFMA GEMM: C[b][m][n] = sum_k A[m][k]*Bt[b][n][k], K=128 ---
// A bf16 [M][128] k-contig (+ aBatch halfs per b); Bt bf16 [b][16384][128].
// OUT_BF16: C bf16 (LDS-staged coalesced stores). else: C fp32 direct stores.
template<int OUT_BF16>
__global__ __launch_bounds__(256) void mfma_gemm(
    const unsigned short* __restrict__ A, long aBatch,
    const unsigned short* __restrict__ Bt, void* __restrict__ Cv, int M)
{
    const int b  = blockIdx.z;
    const int m0 = blockIdx.y * 128;
    const int n0 = blockIdx.x * 128;
    const unsigned short* Ab = A  + (long)b * aBatch + (long)m0 * 128;
    const unsigned short* Bb = Bt + ((long)b * 16384 + n0) * 128;

    __shared__ unsigned short As[128][136];   // +8 halfs pad: 16B-aligned rows, 2-way-free frag reads
    __shared__ unsigned short Bs[128][136];

    const int tid = threadIdx.x;
#pragma unroll
    for (int i = 0; i < 8; ++i) {
        int ch = tid + i * 256;               // 2048 x 16B chunks
        int row = ch >> 4, cg = (ch & 15) * 8;
        *(uint4*)&As[row][cg] = *(const uint4*)&Ab[row * 128 + cg];
        *(uint4*)&Bs[row][cg] = *(const uint4*)&Bb[row * 128 + cg];
    }
    __syncthreads();

    const int l  = tid & 63;
    const int w  = tid >> 6;
    const int mb = (w & 1) * 64, nb = (w >> 1) * 64;
    const int lr = l & 15, lg = l >> 4;

    f32x4 acc[4][4];
    const f32x4 zero = {0.f, 0.f, 0.f, 0.f};
#pragma unroll
    for (int mi = 0; mi < 4; ++mi)
#pragma unroll
        for (int ni = 0; ni < 4; ++ni) acc[mi][ni] = zero;

#pragma unroll
    for (int kk = 0; kk < 128; kk += 32) {
        bf16x8 af[4], bfr[4];
#pragma unroll
        for (int mi = 0; mi < 4; ++mi)
            af[mi] = *(const bf16x8*)&As[mb + mi * 16 + lr][kk + lg * 8];
#pragma unroll
        for (int ni = 0; ni < 4; ++ni)
            bfr[ni] = *(const bf16x8*)&Bs[nb + ni * 16 + lr][kk + lg * 8];
#pragma unroll
        for (int mi = 0; mi < 4; ++mi)
#pragma unroll
            for (int ni = 0; ni < 4; ++ni)
                acc[mi][ni] = __builtin_amdgcn_mfma_f32_16x16x32_bf16(
                    af[mi], bfr[ni], acc[mi][ni], 0, 0, 0);
    }

    if (OUT_BF16) {
        __syncthreads();                       // all waves done reading LDS
        unsigned short* ct = &As[0][0];        // reuse as flat [128][128]
#pragma unroll
        for (int mi = 0; mi < 4; ++mi)
#pragma unroll
            for (int ni = 0; ni < 4; ++ni)
#pragma unroll
                for (int r = 0; r < 4; ++r)
                    ct[(mb + mi * 16 + lg * 4 + r) * 128 + nb + ni * 16 + lr] =
                        f2b(acc[mi][ni][r]);
        __syncthreads();
        unsigned short* Cg = (unsigned short*)Cv + ((long)b * M + m0) * 16384 + n0;
#pragma unroll
        for (int i = 0; i < 8; ++i) {
            int ch = tid + i * 256;
            int row = ch >> 4, cg = (ch & 15) * 8;
            *(uint4*)&Cg[(long)row * 16384 + cg] = *(const uint4*)&ct[row * 128 + cg];
        }
    } else {
        float* Cg = (float*)Cv + ((long)b * M + m0) * 16384 + n0;
#pragma unroll
        for (int mi = 0; mi < 4; ++mi)
#pragma unroll
            for (int ni = 0; ni < 4; ++ni)
#pragma unroll
                for (int r = 0; r < 4; ++r)
                    Cg[(long)(mb + mi * 16 + lg * 4 + r) * 16384 + nb + ni * 16 + lr] =
                        acc[mi][ni][r];
    }
}

// ---------------- depthwise 3x3 + norms + illu gating ----------------------
// qkv1 bf16 in. ch<256 (q,k): write dw'd bf16 -> dwqk, accum sum-of-squares.
// ch>=256 (v): gate with illu, write fp32 -> Vg (= d_out).
__global__ __launch_bounds__(256) void dw_norm_gate(
    const unsigned short* __restrict__ qkv1, const float* __restrict__ wdw,
    const float* __restrict__ illu, float* __restrict__ Vg,
    unsigned short* __restrict__ dwqk, float* __restrict__ nqk)
{
    const int b = blockIdx.z, ch = blockIdx.y;
    const int y0 = blockIdx.x * 8;
    const int tid = threadIdx.x;
    __shared__ float lds[10][130];
    __shared__ float wsum[4];
    const unsigned short* in = qkv1 + ((long)b * 384 + ch) * 16384;

    float wv[9];
#pragma unroll
    for (int j = 0; j < 9; ++j) wv[j] = wdw[ch * 9 + j];

#pragma unroll
    for (int i = 0; i < 5; ++i) {
        int e = tid + i * 256;                // 10 rows * 128
        int row = e >> 7, xx = e & 127;
        int yy = y0 + row - 1;
        lds[row][xx + 1] = (yy >= 0 && yy < 128) ? b2f(in[yy * 128 + xx]) : 0.f;
    }
    if (tid < 10) lds[tid][0] = 0.f;
    else if (tid < 20) lds[tid - 10][129] = 0.f;
    __syncthreads();

    const int x = tid & 127;
    const int rbase = (tid >> 7) * 4;
    float o[4];
#pragma unroll
    for (int rr = 0; rr < 4; ++rr) {
        int ry = rbase + rr;
        float a = 0.f;
#pragma unroll
        for (int ky = 0; ky < 3; ++ky)
#pragma unroll
            for (int kx = 0; kx < 3; ++kx)
                a = fmaf(wv[ky * 3 + kx], lds[ry + ky][x + kx], a);
        o[rr] = a;
    }

    if (ch >= 256) {
        const int c = ch - 256;
        const float* ib = illu + ((long)b * 128 + c) * 16384 + y0 * 128;
        float*       ob = Vg   + ((long)b * 128 + c) * 16384 + y0 * 128;
#pragma unroll
        for (int rr = 0; rr < 4; ++rr) {
            int ry = rbase + rr;
            ob[ry * 128 + x] = o[rr] * ib[ry * 128 + x];
        }
    } else {
        unsigned short* db = dwqk + ((long)b * 256 + ch) * 16384 + y0 * 128;
        float s = 0.f;
#pragma unroll
        for (int rr = 0; rr < 4; ++rr) {
            int ry = rbase + rr;
            unsigned short h = f2b(o[rr]);
            db[ry * 128 + x] = h;
            float f = b2f(h);                  // norms on the ROUNDED values (matches gram)
            s = fmaf(f, f, s);
        }
#pragma unroll
        for (int off = 32; off > 0; off >>= 1) s += __shfl_down(s, off);
        if ((tid & 63) == 0) wsum[tid >> 6] = s;
        __syncthreads();
        if (tid == 0) atomicAdd(&nqk[b * 256 + ch], wsum[0] + wsum[1] + wsum[2] + wsum[3]);
    }
}

// ---------------- gram via MFMA, frags straight from global ----------------
// G[b][hd][c][d] += sum_n dwq[c][n]*dwk[d][n]; per-wave 16x16 frag, K-chunked.
__global__ __launch_bounds__(256) void gram_mfma(const unsigned short* __restrict__ dwqk,
                                                 float* __restrict__ G)
{
    const int hd = blockIdx.y, b = blockIdx.z;
    const int tid = threadIdx.x;
    const int l = tid & 63, w = tid >> 6;
    const int lr = l & 15, lg = l >> 4;
    const unsigned short* qb = dwqk + ((long)b * 256 + hd * 16) * 16384;
    const unsigned short* kb = dwqk + ((long)b * 256 + 128 + hd * 16) * 16384;
    const int n0 = blockIdx.x * 1024 + w * 256;

    f32x4 acc = {0.f, 0.f, 0.f, 0.f};
#pragma unroll
    for (int ks = 0; ks < 8; ++ks) {
        const int n = n0 + ks * 32 + lg * 8;
        bf16x8 a = *(const bf16x8*)&qb[(long)lr * 16384 + n];
        bf16x8 bb = *(const bf16x8*)&kb[(long)lr * 16384 + n];
        acc = __builtin_amdgcn_mfma_f32_16x16x32_bf16(a, bb, acc, 0, 0, 0);
    }

    __shared__ float sg[4][16][16];
#pragma unroll
    for (int r = 0; r < 4; ++r) sg[w][lg * 4 + r][lr] = acc[r];
    __syncthreads();
    const int row = tid >> 4, col = tid & 15;
    float v = sg[0][row][col] + sg[1][row][col] + sg[2][row][col] + sg[3][row][col];
    atomicAdd(&G[(((long)b * 8 + hd) * 16 + row) * 16 + col], v);
}

// -------- attn = softmax( G / (|q_c||k_d|) * temp[hd] ) over d --------------
__global__ void softmax_attn(const float* __restrict__ G, const float* __restrict__ nqk,
                             const float* __restrict__ temp, float* __restrict__ attn)
{
    const int hd = blockIdx.x, b = blockIdx.y;
    const int r = threadIdx.x;
    if (r >= 16) return;
    const float tv = temp[hd];
    const float* g = G + ((long)(b * 8 + hd) * 16 + r) * 16;
    float mq = fmaxf(sqrtf(nqk[b * 256 + hd * 16 + r]), 1e-12f);
    float L[16];
    float mx = -1e30f;
#pragma unroll
    for (int d = 0; d < 16; ++d) {
        float mk = fmaxf(sqrtf(nqk[b * 256 + 128 + hd * 16 + d]), 1e-12f);
        L[d] = g[d] * tv / (mq * mk);
        mx = fmaxf(mx, L[d]);
    }
    float s = 0.f;
#pragma unroll
    for (int d = 0; d < 16; ++d) { L[d] = expf(L[d] - mx); s += L[d]; }
    float inv = 1.f / s;
    float* arow = attn + ((long)(b * 8 + hd) * 16 + r) * 16;
#pragma unroll
    for (int d = 0; d < 16; ++d) arow[d] = L[d] * inv;
}

// ------ CtBo[b][o][D] = sum_c wproj[o][hd(D)*16+c]*attn[b][hd(D)][c][d(D)] --
__global__ __launch_bounds__(256) void compose_kernel(
    const float* __restrict__ wproj, const float* __restrict__ attn,
    unsigned short* __restrict__ CtBo)
{
    const int b = blockIdx.x, tid = threadIdx.x;
#pragma unroll 1
    for (int e = tid; e < 16384; e += 256) {
        const int o = e >> 7, D = e & 127;
        const int hd = D >> 4, d = D & 15;
        const float* ar = attn + (long)(b * 8 + hd) * 256 + d;   // + c*16
        const float* wr = wproj + o * 128 + hd * 16;
        float s = 0.f;
#pragma unroll
        for (int c2 = 0; c2 < 16; ++c2) s = fmaf(wr[c2], ar[c2 * 16], s);
        CtBo[((long)b * 128 + o) * 128 + D] = f2b(s);
    }
}

extern "C" void kernel_launch(void* const* d_in, const int* in_sizes, int n_in,
                              void* d_out, int out_size, void* d_ws, size_t ws_size,
                              hipStream_t stream)
{
    const float* x     = (const float*)d_in[0];
    const float* illu  = (const float*)d_in[1];
    const float* wqkv  = (const float*)d_in[2];
    const float* wdw   = (const float*)d_in[3];
    const float* wproj = (const float*)d_in[4];
    const float* temp  = (const float*)d_in[5];
    float* out = (float*)d_out;
    char*  wsb = (char*)d_ws;

    unsigned short* qkv1 = (unsigned short*)(wsb + OFFB_QKV1);
    unsigned short* dwqk = (unsigned short*)(wsb + OFFB_DWQK);
    unsigned short* xT   = dwqk;                       // alias: xT dead before dwqk written
    unsigned short* VgT  = (unsigned short*)(wsb + OFFB_VGT);
    unsigned short* wbf  = (unsigned short*)(wsb + OFFB_WBF);
    float* G    = (float*)(wsb + OFFB_G);
    float* nqk  = (float*)(wsb + OFFB_NQK);
    float* attn = (float*)(wsb + OFFB_ATTN);
    unsigned short* CtBo = (unsigned short*)(wsb + OFFB_CTB);

    hipLaunchKernelGGL(prep_w, dim3(48), dim3(256), 0, stream, wqkv, wbf);
    hipMemsetAsync(G, 0, 73728, stream);               // G + nqk (contiguous)
    // x -> xT bf16
    hipLaunchKernelGGL(transpose_cb, dim3(256, 4, 8), dim3(256), 0, stream, x, xT);
    // K1: qkv1 = Wqkv @ x (MFMA bf16)
    hipLaunchKernelGGL(HIP_KERNEL_NAME(mfma_gemm<1>), dim3(128, 3, 8), dim3(256), 0, stream,
                       wbf, 0L, xT, (void*)qkv1, 384);
    // K2: dwconv; q,k -> dwqk bf16 + norms; v -> gated fp32 into d_out
    hipLaunchKernelGGL(dw_norm_gate, dim3(16, 384, 8), dim3(256), 0, stream,
                       qkv1, wdw, illu, out, dwqk, nqk);
    // K3: gram via MFMA (overwrote xT region legally)
    hipLaunchKernelGGL(gram_mfma, dim3(16, 8, 8), dim3(256), 0, stream, dwqk, G);
    // K4: normalize + softmax
    hipLaunchKernelGGL(softmax_attn, dim3(8, 8), dim3(64), 0, stream, G, nqk, temp, attn);
    // K5: CtBo = Wproj @ blockdiag(attn), [o][D] bf16 (k-contig for MFMA A)
    hipLaunchKernelGGL(compose_kernel, dim3(8), dim3(256), 0, stream, wproj, attn, CtBo);
    // Vg (in d_out) -> VgT bf16
    hipLaunchKernelGGL(transpose_cb, dim3(256, 4, 8), dim3(256), 0, stream, out, VgT);
    // K6: out = CtBo @ Vgated (MFMA bf16, fp32 out)
    hipLaunchKernelGGL(HIP_KERNEL_NAME(mfma_gemm<0>), dim3(128, 1, 8), dim3(256), 0, stream,
                       CtBo, 16384L, VgT, (void*)out, 128);
}

// Round 4
// 292.644 us; speedup vs baseline: 2.6415x; 1.1885x over previous
//
#include <hip/hip_runtime.h>
#include <hip/hip_bf16.h>

// ---------------- types ----------------
typedef __attribute__((ext_vector_type(8))) short bf16x8;   // 8 bf16 (4 VGPRs)
typedef __attribute__((ext_vector_type(4))) float f32x4;    // MFMA accum

__device__ __forceinline__ unsigned short f2b(float f) {
    unsigned int u = __builtin_bit_cast(unsigned int, f);
    u += 0x7FFFu + ((u >> 16) & 1u);          // RNE
    return (unsigned short)(u >> 16);
}
__device__ __forceinline__ float b2f(unsigned short h) {
    unsigned int u = ((unsigned int)h) << 16;
    return __builtin_bit_cast(float, u);
}

// ---------------- workspace layout (byte offsets) ----------------
// qkv1 bf16 [8][384][16384]                100,663,296 B
// dwqk bf16 [8][256][16384]                 67,108,864 B   (xT bf16 [8][16384][128] aliases its first 33.5MB; xT dead before dwqk written)
// VgT  bf16 [8][16384][128]                 33,554,432 B
// wbf  bf16 [384][128]
// G    f32  [8][8][16][16]
// nqk  f32  [8][256]
// attn f32  [8][8][16][16]
// CtBo bf16 [8][128][128]
// Vg bf16 [8][128][16384] lives in d_out (32MB of 64MB; dead before K6 writes).
#define OFFB_QKV1 0L
#define OFFB_DWQK 100663296L
#define OFFB_VGT  167772160L
#define OFFB_WBF  201326592L
#define OFFB_G    201424896L
#define OFFB_NQK  201490432L
#define OFFB_ATTN 201498624L
#define OFFB_CTB  201564160L

// ---------------- prep: w_qkv fp32 -> bf16 ----------------
__global__ __launch_bounds__(256) void prep_w(const float* __restrict__ w,
                                              unsigned short* __restrict__ wbf)
{
    int e = blockIdx.x * 256 + threadIdx.x;           // < 12288
    float4 v = *(const float4*)&w[e * 4];
    unsigned int p0 = (unsigned int)f2b(v.x) | ((unsigned int)f2b(v.y) << 16);
    unsigned int p1 = (unsigned int)f2b(v.z) | ((unsigned int)f2b(v.w) << 16);
    *(uint2*)&wbf[e * 4] = make_uint2(p0, p1);
}

// ------------- transpose+convert: fp32 [b][128][16384] -> bf16 [b][16384][128]
__global__ __launch_bounds__(256) void transpose_cb(const float* __restrict__ in,
                                                    unsigned short* __restrict__ out)
{
    const int b  = blockIdx.z;
    const int c0 = blockIdx.y * 32;
    const int n0 = blockIdx.x * 64;
    __shared__ float s[32][65];
    const int tid = threadIdx.x;
    const float* ib = in + ((long)b * 128 + c0) * 16384 + n0;
#pragma unroll
    for (int i = 0; i < 2; ++i) {
        int e = tid + i * 256;                        // 0..511 float4 units
        int c = e >> 4, n4 = (e & 15) * 4;
        *(float4*)&s[c][n4] = *(const float4*)&ib[(long)c * 16384 + n4];
    }
    __syncthreads();
    const int n = tid >> 2, cg = (tid & 3) * 8;
    unsigned int p[4];
#pragma unroll
    for (int j = 0; j < 4; ++j)
        p[j] = (unsigned int)f2b(s[cg + 2*j][n]) | ((unsigned int)f2b(s[cg + 2*j + 1][n]) << 16);
    *(uint4*)&out[((long)b * 16384 + n0 + n) * 128 + c0 + cg] = make_uint4(p[0], p[1], p[2], p[3]);
}

// ------------- transpose (bf16 in): [b][128][16384] -> bf16 [b][16384][128]
__global__ __launch_bounds__(256) void transpose_vg(const unsigned short* __restrict__ in,
                                                    unsigned short* __restrict__ out)
{
    const int b  = blockIdx.z;
    const int c0 = blockIdx.y * 32;
    const int n0 = blockIdx.x * 64;
    __shared__ float s[32][65];
    const int tid = threadIdx.x;
    const unsigned short* ib = in + ((long)b * 128 + c0) * 16384 + n0;
    {   // 32 rows x 64 bf16 = 256 chunks of 8 bf16
        int c = tid >> 3, ng = (tid & 7) * 8;
        uint4 v = *(const uint4*)&ib[(long)c * 16384 + ng];
        unsigned int uu[4] = {v.x, v.y, v.z, v.w};
#pragma unroll
        for (int j = 0; j < 4; ++j) {
            s[c][ng + 2*j]     = __builtin_bit_cast(float, uu[j] << 16);
            s[c][ng + 2*j + 1] = __builtin_bit_cast(float, uu[j] & 0xFFFF0000u);
        }
    }
    __syncthreads();
    const int n = tid >> 2, cg = (tid & 3) * 8;
    unsigned int p[4];
#pragma unroll
    for (int j = 0; j < 4; ++j)
        p[j] = (unsigned int)f2b(s[cg + 2*j][n]) | ((unsigned int)f2b(s[cg + 2*j + 1][n]) << 16);
    *(uint4*)&out[((long)b * 16384 + n0 + n) * 128 + c0 + cg] = make_uint4(p[0], p[1], p[2], p[3]);
}

// ---------------- MFMA GEMM: C[b][m][n] = sum_k A[m][k]*Bt[b][n][k], K=128 ---
template<int OUT_BF16>
__global__ __launch_bounds__(256) void mfma_gemm(
    const unsigned short* __restrict__ A, long aBatch,
    const unsigned short* __restrict__ Bt, void* __restrict__ Cv, int M)
{
    const int b  = blockIdx.z;
    const int m0 = blockIdx.y * 128;
    const int n0 = blockIdx.x * 128;
    const unsigned short* Ab = A  + (long)b * aBatch + (long)m0 * 128;
    const unsigned short* Bb = Bt + ((long)b * 16384 + n0) * 128;

    __shared__ unsigned short As[128][136];
    __shared__ unsigned short Bs[128][136];

    const int tid = threadIdx.x;
#pragma unroll
    for (int i = 0; i < 8; ++i) {
        int ch = tid + i * 256;               // 2048 x 16B chunks
        int row = ch >> 4, cg = (ch & 15) * 8;
        *(uint4*)&As[row][cg] = *(const uint4*)&Ab[row * 128 + cg];
        *(uint4*)&Bs[row][cg] = *(const uint4*)&Bb[row * 128 + cg];
    }
    __syncthreads();

    const int l  = tid & 63;
    const int w  = tid >> 6;
    const int mb = (w & 1) * 64, nb = (w >> 1) * 64;
    const int lr = l & 15, lg = l >> 4;

    f32x4 acc[4][4];
    const f32x4 zero = {0.f, 0.f, 0.f, 0.f};
#pragma unroll
    for (int mi = 0; mi < 4; ++mi)
#pragma unroll
        for (int ni = 0; ni < 4; ++ni) acc[mi][ni] = zero;

#pragma unroll
    for (int kk = 0; kk < 128; kk += 32) {
        bf16x8 af[4], bfr[4];
#pragma unroll
        for (int mi = 0; mi < 4; ++mi)
            af[mi] = *(const bf16x8*)&As[mb + mi * 16 + lr][kk + lg * 8];
#pragma unroll
        for (int ni = 0; ni < 4; ++ni)
            bfr[ni] = *(const bf16x8*)&Bs[nb + ni * 16 + lr][kk + lg * 8];
#pragma unroll
        for (int mi = 0; mi < 4; ++mi)
#pragma unroll
            for (int ni = 0; ni < 4; ++ni)
                acc[mi][ni] = __builtin_amdgcn_mfma_f32_16x16x32_bf16(
                    af[mi], bfr[ni], acc[mi][ni], 0, 0, 0);
    }

    if (OUT_BF16) {
        __syncthreads();
        unsigned short* ct = &As[0][0];        // reuse as flat [128][128]
#pragma unroll
        for (int mi = 0; mi < 4; ++mi)
#pragma unroll
            for (int ni = 0; ni < 4; ++ni)
#pragma unroll
                for (int r = 0; r < 4; ++r)
                    ct[(mb + mi * 16 + lg * 4 + r) * 128 + nb + ni * 16 + lr] =
                        f2b(acc[mi][ni][r]);
        __syncthreads();
        unsigned short* Cg = (unsigned short*)Cv + ((long)b * M + m0) * 16384 + n0;
#pragma unroll
        for (int i = 0; i < 8; ++i) {
            int ch = tid + i * 256;
            int row = ch >> 4, cg = (ch & 15) * 8;
            *(uint4*)&Cg[(long)row * 16384 + cg] = *(const uint4*)&ct[row * 128 + cg];
        }
    } else {
        float* Cg = (float*)Cv + ((long)b * M + m0) * 16384 + n0;
#pragma unroll
        for (int mi = 0; mi < 4; ++mi)
#pragma unroll
            for (int ni = 0; ni < 4; ++ni)
#pragma unroll
                for (int r = 0; r < 4; ++r)
                    Cg[(long)(mb + mi * 16 + lg * 4 + r) * 16384 + nb + ni * 16 + lr] =
                        acc[mi][ni][r];
    }
}

// ---------------- depthwise 3x3 + norms + illu gating ----------------------
// 16-row strips, vectorized bf16 staging, 8 outputs/thread (sliding window).
// ch<256 (q,k): write dw'd bf16 -> dwqk, accum sum-of-squares into nqk.
// ch>=256 (v): gate with illu, write bf16 -> Vg (= d_out as bf16).
__global__ __launch_bounds__(256) void dw_norm_gate(
    const unsigned short* __restrict__ qkv1, const float* __restrict__ wdw,
    const float* __restrict__ illu, unsigned short* __restrict__ Vg,
    unsigned short* __restrict__ dwqk, float* __restrict__ nqk)
{
    const int b = blockIdx.z, ch = blockIdx.y;
    const int y0 = blockIdx.x * 16;
    const int tid = threadIdx.x;
    // data cols at [4..131]; [3] and [132] are the zero halo (16B-aligned stores)
    __shared__ float lds[18][136];
    __shared__ float wsum[4];
    const unsigned short* in = qkv1 + ((long)b * 384 + ch) * 16384;

    float wv[9];
#pragma unroll
    for (int j = 0; j < 9; ++j) wv[j] = wdw[ch * 9 + j];

    // stage 18 rows x 128 cols = 288 chunks of 8 bf16
#pragma unroll
    for (int i = 0; i < 2; ++i) {
        int chk = tid + i * 256;
        if (chk < 288) {
            int row = chk >> 4, xg = (chk & 15) * 8;
            int yy = y0 + row - 1;
            float f[8];
            if (yy >= 0 && yy < 128) {
                uint4 v = *(const uint4*)&in[yy * 128 + xg];
                unsigned int uu[4] = {v.x, v.y, v.z, v.w};
#pragma unroll
                for (int j = 0; j < 4; ++j) {
                    f[2*j]   = __builtin_bit_cast(float, uu[j] << 16);
                    f[2*j+1] = __builtin_bit_cast(float, uu[j] & 0xFFFF0000u);
                }
            } else {
#pragma unroll
                for (int j = 0; j < 8; ++j) f[j] = 0.f;
            }
            *(float4*)&lds[row][xg + 4] = make_float4(f[0], f[1], f[2], f[3]);
            *(float4*)&lds[row][xg + 8] = make_float4(f[4], f[5], f[6], f[7]);
        }
    }
    if (tid < 18) lds[tid][3] = 0.f;
    else if (tid < 50 && tid >= 32) lds[tid - 32][132] = 0.f;
    __syncthreads();

    const int x  = tid & 127;
    const int rt = (tid >> 7) * 8;            // 0 or 8
    float c0[10], c1[10], c2[10];
#pragma unroll
    for (int t = 0; t < 10; ++t) {
        c0[t] = lds[rt + t][x + 3];
        c1[t] = lds[rt + t][x + 4];
        c2[t] = lds[rt + t][x + 5];
    }
    float o[8];
#pragma unroll
    for (int rr = 0; rr < 8; ++rr) {
        float a = 0.f;
        a = fmaf(wv[0], c0[rr],     a); a = fmaf(wv[1], c1[rr],     a); a = fmaf(wv[2], c2[rr],     a);
        a = fmaf(wv[3], c0[rr + 1], a); a = fmaf(wv[4], c1[rr + 1], a); a = fmaf(wv[5], c2[rr + 1], a);
        a = fmaf(wv[6], c0[rr + 2], a); a = fmaf(wv[7], c1[rr + 2], a); a = fmaf(wv[8], c2[rr + 2], a);
        o[rr] = a;
    }

    if (ch >= 256) {
        const int c = ch - 256;
        const float* ib = illu + ((long)b * 128 + c) * 16384 + y0 * 128;
        unsigned short* ob = Vg + ((long)b * 128 + c) * 16384 + y0 * 128;
#pragma unroll
        for (int rr = 0; rr < 8; ++rr) {
            int ry = rt + rr;
            ob[ry * 128 + x] = f2b(o[rr] * ib[ry * 128 + x]);
        }
    } else {
        unsigned short* db = dwqk + ((long)b * 256 + ch) * 16384 + y0 * 128;
        float s = 0.f;
#pragma unroll
        for (int rr = 0; rr < 8; ++rr) {
            int ry = rt + rr;
            unsigned short h = f2b(o[rr]);
            db[ry * 128 + x] = h;
            float f = b2f(h);                  // norms on the ROUNDED values (matches gram)
            s = fmaf(f, f, s);
        }
#pragma unroll
        for (int off = 32; off > 0; off >>= 1) s += __shfl_down(s, off);
        if ((tid & 63) == 0) wsum[tid >> 6] = s;
        __syncthreads();
        if (tid == 0) atomicAdd(&nqk[b * 256 + ch], wsum[0] + wsum[1] + wsum[2] + wsum[3]);
    }
}

// ---------------- gram via MFMA, frags straight from global ----------------
__global__ __launch_bounds__(256) void gram_mfma(const unsigned short* __restrict__ dwqk,
                                                 float* __restrict__ G)
{
    const int hd = blockIdx.y, b = blockIdx.z;
    const int tid = threadIdx.x;
    const int l = tid & 63, w = tid >> 6;
    const int lr = l & 15, lg = l >> 4;
    const unsigned short* qb = dwqk + ((long)b * 256 + hd * 16) * 16384;
    const unsigned short* kb = dwqk + ((long)b * 256 + 128 + hd * 16) * 16384;
    const int n0 = blockIdx.x * 1024 + w * 256;

    f32x4 acc = {0.f, 0.f, 0.f, 0.f};
#pragma unroll
    for (int ks = 0; ks < 8; ++ks) {
        const int n = n0 + ks * 32 + lg * 8;
        bf16x8 a = *(const bf16x8*)&qb[(long)lr * 16384 + n];
        bf16x8 bb = *(const bf16x8*)&kb[(long)lr * 16384 + n];
        acc = __builtin_amdgcn_mfma_f32_16x16x32_bf16(a, bb, acc, 0, 0, 0);
    }

    __shared__ float sg[4][16][16];
#pragma unroll
    for (int r = 0; r < 4; ++r) sg[w][lg * 4 + r][lr] = acc[r];
    __syncthreads();
    const int row = tid >> 4, col = tid & 15;
    float v = sg[0][row][col] + sg[1][row][col] + sg[2][row][col] + sg[3][row][col];
    atomicAdd(&G[(((long)b * 8 + hd) * 16 + row) * 16 + col], v);
}

// -------- attn = softmax( G / (|q_c||k_d|) * temp[hd] ) over d --------------
__global__ void softmax_attn(const float* __restrict__ G, const float* __restrict__ nqk,
                             const float* __restrict__ temp, float* __restrict__ attn)
{
    const int hd = blockIdx.x, b = blockIdx.y;
    const int r = threadIdx.x;
    if (r >= 16) return;
    const float tv = temp[hd];
    const float* g = G + ((long)(b * 8 + hd) * 16 + r) * 16;
    float mq = fmaxf(sqrtf(nqk[b * 256 + hd * 16 + r]), 1e-12f);
    float L[16];
    float mx = -1e30f;
#pragma unroll
    for (int d = 0; d < 16; ++d) {
        float mk = fmaxf(sqrtf(nqk[b * 256 + 128 + hd * 16 + d]), 1e-12f);
        L[d] = g[d] * tv / (mq * mk);
        mx = fmaxf(mx, L[d]);
    }
    float s = 0.f;
#pragma unroll
    for (int d = 0; d < 16; ++d) { L[d] = expf(L[d] - mx); s += L[d]; }
    float inv = 1.f / s;
    float* arow = attn + ((long)(b * 8 + hd) * 16 + r) * 16;
#pragma unroll
    for (int d = 0; d < 16; ++d) arow[d] = L[d] * inv;
}

// ------ CtBo[b][o][D] = sum_c wproj[o][hd(D)*16+c]*attn[b][hd(D)][c][d(D)] --
__global__ __launch_bounds__(256) void compose_kernel(
    const float* __restrict__ wproj, const float* __restrict__ attn,
    unsigned short* __restrict__ CtBo)
{
    const int b = blockIdx.x, tid = threadIdx.x;
#pragma unroll 1
    for (int e = tid; e < 16384; e += 256) {
        const int o = e >> 7, D = e & 127;
        const int hd = D >> 4, d = D & 15;
        const float* ar = attn + (long)(b * 8 + hd) * 256 + d;   // + c*16
        const float* wr = wproj + o * 128 + hd * 16;
        float s = 0.f;
#pragma unroll
        for (int c2 = 0; c2 < 16; ++c2) s = fmaf(wr[c2], ar[c2 * 16], s);
        CtBo[((long)b * 128 + o) * 128 + D] = f2b(s);
    }
}

extern "C" void kernel_launch(void* const* d_in, const int* in_sizes, int n_in,
                              void* d_out, int out_size, void* d_ws, size_t ws_size,
                              hipStream_t stream)
{
    const float* x     = (const float*)d_in[0];
    const float* illu  = (const float*)d_in[1];
    const float* wqkv  = (const float*)d_in[2];
    const float* wdw   = (const float*)d_in[3];
    const float* wproj = (const float*)d_in[4];
    const float* temp  = (const float*)d_in[5];
    float* out = (float*)d_out;
    char*  wsb = (char*)d_ws;

    unsigned short* qkv1 = (unsigned short*)(wsb + OFFB_QKV1);
    unsigned short* dwqk = (unsigned short*)(wsb + OFFB_DWQK);
    unsigned short* xT   = dwqk;                       // alias: xT dead before dwqk written
    unsigned short* VgT  = (unsigned short*)(wsb + OFFB_VGT);
    unsigned short* wbf  = (unsigned short*)(wsb + OFFB_WBF);
    float* G    = (float*)(wsb + OFFB_G);
    float* nqk  = (float*)(wsb + OFFB_NQK);
    float* attn = (float*)(wsb + OFFB_ATTN);
    unsigned short* CtBo = (unsigned short*)(wsb + OFFB_CTB);
    unsigned short* Vg   = (unsigned short*)d_out;     // bf16 scratch in d_out (32MB of 64MB)

    hipLaunchKernelGGL(prep_w, dim3(48), dim3(256), 0, stream, wqkv, wbf);
    hipMemsetAsync(G, 0, 73728, stream);               // G + nqk (contiguous)
    // x -> xT bf16
    hipLaunchKernelGGL(transpose_cb, dim3(256, 4, 8), dim3(256), 0, stream, x, xT);
    // K1: qkv1 = Wqkv @ x (MFMA bf16)
    hipLaunchKernelGGL(HIP_KERNEL_NAME(mfma_gemm<1>), dim3(128, 3, 8), dim3(256), 0, stream,
                       wbf, 0L, xT, (void*)qkv1, 384);
    // K2: dwconv; q,k -> dwqk bf16 + norms; v -> gated bf16 into d_out
    hipLaunchKernelGGL(dw_norm_gate, dim3(8, 384, 8), dim3(256), 0, stream,
                       qkv1, wdw, illu, Vg, dwqk, nqk);
    // K3: gram via MFMA
    hipLaunchKernelGGL(gram_mfma, dim3(16, 8, 8), dim3(256), 0, stream, dwqk, G);
    // K4: normalize + softmax
    hipLaunchKernelGGL(softmax_attn, dim3(8, 8), dim3(64), 0, stream, G, nqk, temp, attn);
    // K5: CtBo = Wproj @ blockdiag(attn), [o][D] bf16 (k-contig for MFMA A)
    hipLaunchKernelGGL(compose_kernel, dim3(8), dim3(256), 0, stream, wproj, attn, CtBo);
    // Vg (bf16 in d_out) -> VgT bf16
    hipLaunchKernelGGL(transpose_vg, dim3(256, 4, 8), dim3(256), 0, stream, Vg, VgT);
    // K6: out = CtBo @ Vgated (MFMA bf16, fp32 out; overwrites all of d_out)
    hipLaunchKernelGGL(HIP_KERNEL_NAME(mfma_gemm<0>), dim3(128, 1, 8), dim3(256), 0, stream,
                       CtBo, 16384L, VgT, (void*)out, 128);
}

// Round 5
// 280.737 us; speedup vs baseline: 2.7535x; 1.0424x over previous
//
#include <hip/hip_runtime.h>
#include <hip/hip_bf16.h>

// ---------------- types ----------------
typedef __attribute__((ext_vector_type(8))) short bf16x8;   // 8 bf16 (4 VGPRs)
typedef __attribute__((ext_vector_type(4))) float f32x4;    // MFMA accum

__device__ __forceinline__ unsigned short f2b(float f) {
    unsigned int u = __builtin_bit_cast(unsigned int, f);
    u += 0x7FFFu + ((u >> 16) & 1u);          // RNE
    return (unsigned short)(u >> 16);
}
__device__ __forceinline__ float b2f(unsigned short h) {
    unsigned int u = ((unsigned int)h) << 16;
    return __builtin_bit_cast(float, u);
}

// ---------------- workspace layout (byte offsets) ----------------
// qkv1 bf16 [8][384][16384]                100,663,296 B
// slot2: xT bf16 [8][16384][128] (33.5MB) until K1; then Vg bf16 [8][128][16384]
//        (33.5MB) written by dw_v_gate. xT fully dead before Vg written.
// wbf  bf16 [384][128]
// G    f32  [8][8][16][16]   (zeroed in prep)
// nqk  f32  [8][256]         (zeroed in prep, contiguous after G)
// CtBo bf16 [8][128][128]
#define OFFB_QKV1 0L
#define OFFB_SLOT2 100663296L
#define OFFB_WBF  201326592L
#define OFFB_G    201424896L
#define OFFB_NQK  201490432L
#define OFFB_CTB  201564160L

// ---------------- prep: w_qkv fp32 -> bf16; zero G+nqk ----------------
__global__ __launch_bounds__(256) void prep_w_zero(const float* __restrict__ w,
                                                   unsigned short* __restrict__ wbf,
                                                   float* __restrict__ Gz)
{
    if (blockIdx.x < 48) {
        int e = blockIdx.x * 256 + threadIdx.x;       // < 12288
        float4 v = *(const float4*)&w[e * 4];
        unsigned int p0 = (unsigned int)f2b(v.x) | ((unsigned int)f2b(v.y) << 16);
        unsigned int p1 = (unsigned int)f2b(v.z) | ((unsigned int)f2b(v.w) << 16);
        *(uint2*)&wbf[e * 4] = make_uint2(p0, p1);
    } else {
        // zero G (16384 f) + nqk (2048 f) = 18432 floats
        for (int i = threadIdx.x; i < 18432; i += 256) Gz[i] = 0.f;
    }
}

// ------------- transpose+convert: fp32 [b][128][16384] -> bf16 [b][16384][128]
__global__ __launch_bounds__(256) void transpose_cb(const float* __restrict__ in,
                                                    unsigned short* __restrict__ out)
{
    const int b  = blockIdx.z;
    const int c0 = blockIdx.y * 32;
    const int n0 = blockIdx.x * 64;
    __shared__ float s[32][65];
    const int tid = threadIdx.x;
    const float* ib = in + ((long)b * 128 + c0) * 16384 + n0;
#pragma unroll
    for (int i = 0; i < 2; ++i) {
        int e = tid + i * 256;                        // 0..511 float4 units
        int c = e >> 4, n4 = (e & 15) * 4;
        *(float4*)&s[c][n4] = *(const float4*)&ib[(long)c * 16384 + n4];
    }
    __syncthreads();
    const int n = tid >> 2, cg = (tid & 3) * 8;
    unsigned int p[4];
#pragma unroll
    for (int j = 0; j < 4; ++j)
        p[j] = (unsigned int)f2b(s[cg + 2*j][n]) | ((unsigned int)f2b(s[cg + 2*j + 1][n]) << 16);
    *(uint4*)&out[((long)b * 16384 + n0 + n) * 128 + c0 + cg] = make_uint4(p[0], p[1], p[2], p[3]);
}

// ---------------- K1 MFMA GEMM: C[b][m][n] = sum_k A[m][k]*Bt[b][n][k] -------
// A bf16 [384][128] k-contig shared across b; Bt bf16 [b][16384][128]; C bf16.
__global__ __launch_bounds__(256) void mfma_gemm_k1(
    const unsigned short* __restrict__ A,
    const unsigned short* __restrict__ Bt, unsigned short* __restrict__ C)
{
    const int b  = blockIdx.z;
    const int m0 = blockIdx.y * 128;
    const int n0 = blockIdx.x * 128;
    const unsigned short* Ab = A + (long)m0 * 128;
    const unsigned short* Bb = Bt + ((long)b * 16384 + n0) * 128;

    __shared__ unsigned short As[128][136];
    __shared__ unsigned short Bs[128][136];

    const int tid = threadIdx.x;
#pragma unroll
    for (int i = 0; i < 8; ++i) {
        int ch = tid + i * 256;               // 2048 x 16B chunks
        int row = ch >> 4, cg = (ch & 15) * 8;
        *(uint4*)&As[row][cg] = *(const uint4*)&Ab[row * 128 + cg];
        *(uint4*)&Bs[row][cg] = *(const uint4*)&Bb[row * 128 + cg];
    }
    __syncthreads();

    const int l  = tid & 63;
    const int w  = tid >> 6;
    const int mb = (w & 1) * 64, nb = (w >> 1) * 64;
    const int lr = l & 15, lg = l >> 4;

    f32x4 acc[4][4];
    const f32x4 zero = {0.f, 0.f, 0.f, 0.f};
#pragma unroll
    for (int mi = 0; mi < 4; ++mi)
#pragma unroll
        for (int ni = 0; ni < 4; ++ni) acc[mi][ni] = zero;

#pragma unroll
    for (int kk = 0; kk < 128; kk += 32) {
        bf16x8 af[4], bfr[4];
#pragma unroll
        for (int mi = 0; mi < 4; ++mi)
            af[mi] = *(const bf16x8*)&As[mb + mi * 16 + lr][kk + lg * 8];
#pragma unroll
        for (int ni = 0; ni < 4; ++ni)
            bfr[ni] = *(const bf16x8*)&Bs[nb + ni * 16 + lr][kk + lg * 8];
#pragma unroll
        for (int mi = 0; mi < 4; ++mi)
#pragma unroll
            for (int ni = 0; ni < 4; ++ni)
                acc[mi][ni] = __builtin_amdgcn_mfma_f32_16x16x32_bf16(
                    af[mi], bfr[ni], acc[mi][ni], 0, 0, 0);
    }

    __syncthreads();
    unsigned short* ct = &As[0][0];            // reuse as flat [128][128]
#pragma unroll
    for (int mi = 0; mi < 4; ++mi)
#pragma unroll
        for (int ni = 0; ni < 4; ++ni)
#pragma unroll
            for (int r = 0; r < 4; ++r)
                ct[(mb + mi * 16 + lg * 4 + r) * 128 + nb + ni * 16 + lr] =
                    f2b(acc[mi][ni][r]);
    __syncthreads();
    unsigned short* Cg = C + ((long)b * 384 + m0) * 16384 + n0;
#pragma unroll
    for (int i = 0; i < 8; ++i) {
        int ch = tid + i * 256;
        int row = ch >> 4, cg = (ch & 15) * 8;
        *(uint4*)&Cg[(long)row * 16384 + cg] = *(const uint4*)&ct[row * 128 + cg];
    }
}

// ---------------- fused dwconv(q,k) + norms + gram MFMA --------------------
// grid (16 strips of 8 rows, 8 heads, 8 b), 256 threads (4 waves).
// Stages [10][130][18] u16 (x-padded halo); builds MFMA frags in registers.
__global__ __launch_bounds__(256) void dw_qk_gram(
    const unsigned short* __restrict__ qkv1, const float* __restrict__ wdw,
    float* __restrict__ G, float* __restrict__ nqk)
{
    const int strip = blockIdx.x, hd = blockIdx.y, b = blockIdx.z;
    const int y0 = strip * 8;
    const int tid = threadIdx.x;
    const int l = tid & 63, w = tid >> 6;
    const int lr = l & 15, lg = l >> 4;

    __shared__ unsigned short st[10][130][18];
    __shared__ float sg[4][16][16];

    // zero x-halo columns (padded x index 0 and 129)
    if (tid < 180) {
        int y = tid / 18, c = tid - y * 18;
        st[y][0][c] = 0; st[y][129][c] = 0;
    }

    const int sch = tid & 15;       // staged channel
    const int sxc = tid >> 4;       // x-chunk (8 halfs each)

    bf16x8 af[8];
    f32x4 acc = {0.f, 0.f, 0.f, 0.f};
    float qn = 0.f, kn = 0.f;

    for (int op = 0; op < 2; ++op) {
        const int chbase = op * 128 + hd * 16;
        __syncthreads();                       // halo done / prior frag reads done
        const unsigned short* src = qkv1 + ((long)b * 384 + chbase + sch) * 16384;
#pragma unroll
        for (int y = 0; y < 10; ++y) {
            int yy = y0 + y - 1;
            uint4 v = make_uint4(0, 0, 0, 0);
            if (yy >= 0 && yy < 128) v = *(const uint4*)&src[yy * 128 + sxc * 8];
            unsigned short* d = &st[y][sxc * 8 + 1][sch];
            d[0]   = (unsigned short)(v.x);
            d[18]  = (unsigned short)(v.x >> 16);
            d[36]  = (unsigned short)(v.y);
            d[54]  = (unsigned short)(v.y >> 16);
            d[72]  = (unsigned short)(v.z);
            d[90]  = (unsigned short)(v.z >> 16);
            d[108] = (unsigned short)(v.w);
            d[126] = (unsigned short)(v.w >> 16);
        }
        __syncthreads();

        float wv[9];
#pragma unroll
        for (int j = 0; j < 9; ++j) wv[j] = wdw[(chbase + lr) * 9 + j];

#pragma unroll
        for (int j = 0; j < 8; ++j) {
            const int yb = 2 * w + (j >> 2);          // staged row of tap -1
            const int x0 = (j & 3) * 32 + lg * 8;     // padded tap base
            float r0[10], r1[10], r2[10];
#pragma unroll
            for (int i = 0; i < 10; ++i) {
                r0[i] = b2f(st[yb][x0 + i][lr]);
                r1[i] = b2f(st[yb + 1][x0 + i][lr]);
                r2[i] = b2f(st[yb + 2][x0 + i][lr]);
            }
            bf16x8 fr;
            float nrm = 0.f;
#pragma unroll
            for (int i = 0; i < 8; ++i) {
                float a = 0.f;
                a = fmaf(wv[0], r0[i], a); a = fmaf(wv[1], r0[i+1], a); a = fmaf(wv[2], r0[i+2], a);
                a = fmaf(wv[3], r1[i], a); a = fmaf(wv[4], r1[i+1], a); a = fmaf(wv[5], r1[i+2], a);
                a = fmaf(wv[6], r2[i], a); a = fmaf(wv[7], r2[i+1], a); a = fmaf(wv[8], r2[i+2], a);
                unsigned short hh = f2b(a);
                fr[i] = (short)hh;
                float f = b2f(hh);                    // norms on rounded values
                nrm = fmaf(f, f, nrm);
            }
            if (op == 0) { af[j] = fr; qn += nrm; }
            else {
                kn += nrm;
                acc = __builtin_amdgcn_mfma_f32_16x16x32_bf16(af[j], fr, acc, 0, 0, 0);
            }
        }
    }

    // norms: reduce across lg groups (lanes sharing lr)
    qn += __shfl_xor(qn, 16); qn += __shfl_xor(qn, 32);
    kn += __shfl_xor(kn, 16); kn += __shfl_xor(kn, 32);
    if (l < 16) {
        atomicAdd(&nqk[b * 256 + hd * 16 + lr], qn);
        atomicAdd(&nqk[b * 256 + 128 + hd * 16 + lr], kn);
    }

    // gram: reduce 4 waves then atomic
#pragma unroll
    for (int r = 0; r < 4; ++r) sg[w][lg * 4 + r][lr] = acc[r];
    __syncthreads();
    const int row = tid >> 4, col = tid & 15;
    float v = sg[0][row][col] + sg[1][row][col] + sg[2][row][col] + sg[3][row][col];
    atomicAdd(&G[(((long)b * 8 + hd) * 16 + row) * 16 + col], v);
}

// ---------------- depthwise 3x3 (v) + illu gating -> Vg bf16 [c][n] --------
__global__ __launch_bounds__(256) void dw_v_gate(
    const unsigned short* __restrict__ qkv1, const float* __restrict__ wdw,
    const float* __restrict__ illu, unsigned short* __restrict__ Vg)
{
    const int b = blockIdx.z, c = blockIdx.y;
    const int ch = 256 + c;
    const int y0 = blockIdx.x * 16;
    const int tid = threadIdx.x;
    __shared__ float lds[18][136];
    const unsigned short* in = qkv1 + ((long)b * 384 + ch) * 16384;

    float wv[9];
#pragma unroll
    for (int j = 0; j < 9; ++j) wv[j] = wdw[ch * 9 + j];

#pragma unroll
    for (int i = 0; i < 2; ++i) {
        int chk = tid + i * 256;
        if (chk < 288) {
            int row = chk >> 4, xg = (chk & 15) * 8;
            int yy = y0 + row - 1;
            float f[8];
            if (yy >= 0 && yy < 128) {
                uint4 v = *(const uint4*)&in[yy * 128 + xg];
                unsigned int uu[4] = {v.x, v.y, v.z, v.w};
#pragma unroll
                for (int j = 0; j < 4; ++j) {
                    f[2*j]   = __builtin_bit_cast(float, uu[j] << 16);
                    f[2*j+1] = __builtin_bit_cast(float, uu[j] & 0xFFFF0000u);
                }
            } else {
#pragma unroll
                for (int j = 0; j < 8; ++j) f[j] = 0.f;
            }
            *(float4*)&lds[row][xg + 4] = make_float4(f[0], f[1], f[2], f[3]);
            *(float4*)&lds[row][xg + 8] = make_float4(f[4], f[5], f[6], f[7]);
        }
    }
    if (tid < 18) lds[tid][3] = 0.f;
    else if (tid < 50 && tid >= 32) lds[tid - 32][132] = 0.f;
    __syncthreads();

    const int x  = tid & 127;
    const int rt = (tid >> 7) * 8;            // 0 or 8
    float c0[10], c1[10], c2[10];
#pragma unroll
    for (int t = 0; t < 10; ++t) {
        c0[t] = lds[rt + t][x + 3];
        c1[t] = lds[rt + t][x + 4];
        c2[t] = lds[rt + t][x + 5];
    }
    const float* ib = illu + ((long)b * 128 + c) * 16384 + y0 * 128;
    unsigned short* ob = Vg + ((long)b * 128 + c) * 16384 + y0 * 128;
#pragma unroll
    for (int rr = 0; rr < 8; ++rr) {
        float a = 0.f;
        a = fmaf(wv[0], c0[rr],     a); a = fmaf(wv[1], c1[rr],     a); a = fmaf(wv[2], c2[rr],     a);
        a = fmaf(wv[3], c0[rr + 1], a); a = fmaf(wv[4], c1[rr + 1], a); a = fmaf(wv[5], c2[rr + 1], a);
        a = fmaf(wv[6], c0[rr + 2], a); a = fmaf(wv[7], c1[rr + 2], a); a = fmaf(wv[8], c2[rr + 2], a);
        int ry = rt + rr;
        ob[ry * 128 + x] = f2b(a * ib[ry * 128 + x]);
    }
}

// ------ fused softmax + compose: CtBo[b][o][D] ------------------------------
__global__ __launch_bounds__(256) void softmax_compose(
    const float* __restrict__ G, const float* __restrict__ nqk,
    const float* __restrict__ temp, const float* __restrict__ wproj,
    unsigned short* __restrict__ CtBo)
{
    const int b = blockIdx.x;
    const int tid = threadIdx.x;
    __shared__ float sa[8][16][16];
    if (tid < 128) {
        const int hd = tid >> 4, r = tid & 15;
        const float tv = temp[hd];
        const float* g = G + ((long)(b * 8 + hd) * 16 + r) * 16;
        float mq = fmaxf(sqrtf(nqk[b * 256 + hd * 16 + r]), 1e-12f);
        float L[16];
        float mx = -1e30f;
#pragma unroll
        for (int d = 0; d < 16; ++d) {
            float mk = fmaxf(sqrtf(nqk[b * 256 + 128 + hd * 16 + d]), 1e-12f);
            L[d] = g[d] * tv / (mq * mk);
            mx = fmaxf(mx, L[d]);
        }
        float s = 0.f;
#pragma unroll
        for (int d = 0; d < 16; ++d) { L[d] = expf(L[d] - mx); s += L[d]; }
        float inv = 1.f / s;
#pragma unroll
        for (int d = 0; d < 16; ++d) sa[hd][r][d] = L[d] * inv;
    }
    __syncthreads();
#pragma unroll 1
    for (int e = tid; e < 16384; e += 256) {
        const int o = e >> 7, D = e & 127;
        const int hd2 = D >> 4, d = D & 15;
        const float* wr = wproj + o * 128 + hd2 * 16;
        float s = 0.f;
#pragma unroll
        for (int c2 = 0; c2 < 16; ++c2) s = fmaf(wr[c2], sa[hd2][c2][d], s);
        CtBo[((long)b * 128 + o) * 128 + D] = f2b(s);
    }
}

// ------ K6: out[b][o][n] = sum_D CtBo[b][o][D] * Vg[b][D][n] ---------------
// In-kernel transpose of Vg tile (via [32][65]-float LDS), fp32 out.
__global__ __launch_bounds__(256) void mfma_k6(
    const unsigned short* __restrict__ CtBo, const unsigned short* __restrict__ Vg,
    float* __restrict__ out)
{
    const int b  = blockIdx.y;
    const int n0 = blockIdx.x * 128;
    __shared__ unsigned short As[128][136];
    __shared__ unsigned short Bs[128][136];
    __shared__ float sfl[32][65];
    const int tid = threadIdx.x;

    const unsigned short* Ab = CtBo + (long)b * 16384;
#pragma unroll
    for (int i = 0; i < 8; ++i) {
        int ch = tid + i * 256;
        int row = ch >> 4, cg = (ch & 15) * 8;
        *(uint4*)&As[row][cg] = *(const uint4*)&Ab[row * 128 + cg];
    }

    const unsigned short* Vb = Vg + (long)b * 128 * 16384;
#pragma unroll 1
    for (int it = 0; it < 8; ++it) {
        const int c0 = (it & 3) * 32, nb0 = (it >> 2) * 64;
        {
            int c = tid >> 3, n8 = (tid & 7) * 8;
            uint4 v = *(const uint4*)&Vb[(long)(c0 + c) * 16384 + n0 + nb0 + n8];
            unsigned int uu[4] = {v.x, v.y, v.z, v.w};
#pragma unroll
            for (int j = 0; j < 4; ++j) {
                sfl[c][n8 + 2*j]     = __builtin_bit_cast(float, uu[j] << 16);
                sfl[c][n8 + 2*j + 1] = __builtin_bit_cast(float, uu[j] & 0xFFFF0000u);
            }
        }
        __syncthreads();
        {
            int n = tid >> 2, cg = (tid & 3) * 8;
            unsigned int p[4];
#pragma unroll
            for (int j = 0; j < 4; ++j)
                p[j] = (unsigned int)f2b(sfl[cg + 2*j][n]) | ((unsigned int)f2b(sfl[cg + 2*j + 1][n]) << 16);
            *(uint4*)&Bs[nb0 + n][c0 + cg] = make_uint4(p[0], p[1], p[2], p[3]);
        }
        __syncthreads();
    }

    const int l  = tid & 63;
    const int w  = tid >> 6;
    const int mb = (w & 1) * 64, nb = (w >> 1) * 64;
    const int lr = l & 15, lg = l >> 4;

    f32x4 acc[4][4];
    const f32x4 zero = {0.f, 0.f, 0.f, 0.f};
#pragma unroll
    for (int mi = 0; mi < 4; ++mi)
#pragma unroll
        for (int ni = 0; ni < 4; ++ni) acc[mi][ni] = zero;

#pragma unroll
    for (int kk = 0; kk < 128; kk += 32) {
        bf16x8 af[4], bfr[4];
#pragma unroll
        for (int mi = 0; mi < 4; ++mi)
            af[mi] = *(const bf16x8*)&As[mb + mi * 16 + lr][kk + lg * 8];
#pragma unroll
        for (int ni = 0; ni < 4; ++ni)
            bfr[ni] = *(const bf16x8*)&Bs[nb + ni * 16 + lr][kk + lg * 8];
#pragma unroll
        for (int mi = 0; mi < 4; ++mi)
#pragma unroll
            for (int ni = 0; ni < 4; ++ni)
                acc[mi][ni] = __builtin_amdgcn_mfma_f32_16x16x32_bf16(
                    af[mi], bfr[ni], acc[mi][ni], 0, 0, 0);
    }

    float* Cg = out + ((long)b * 128) * 16384 + n0;
#pragma unroll
    for (int mi = 0; mi < 4; ++mi)
#pragma unroll
        for (int ni = 0; ni < 4; ++ni)
#pragma unroll
            for (int r = 0; r < 4; ++r)
                Cg[(long)(mb + mi * 16 + lg * 4 + r) * 16384 + nb + ni * 16 + lr] =
                    acc[mi][ni][r];
}

extern "C" void kernel_launch(void* const* d_in, const int* in_sizes, int n_in,
                              void* d_out, int out_size, void* d_ws, size_t ws_size,
                              hipStream_t stream)
{
    const float* x     = (const float*)d_in[0];
    const float* illu  = (const float*)d_in[1];
    const float* wqkv  = (const float*)d_in[2];
    const float* wdw   = (const float*)d_in[3];
    const float* wproj = (const float*)d_in[4];
    const float* temp  = (const float*)d_in[5];
    float* out = (float*)d_out;
    char*  wsb = (char*)d_ws;

    unsigned short* qkv1 = (unsigned short*)(wsb + OFFB_QKV1);
    unsigned short* xT   = (unsigned short*)(wsb + OFFB_SLOT2);  // dead after K1
    unsigned short* Vg   = (unsigned short*)(wsb + OFFB_SLOT2);  // written after K1
    unsigned short* wbf  = (unsigned short*)(wsb + OFFB_WBF);
    float* G    = (float*)(wsb + OFFB_G);
    float* nqk  = (float*)(wsb + OFFB_NQK);
    unsigned short* CtBo = (unsigned short*)(wsb + OFFB_CTB);

    // prep: w->bf16 + zero G/nqk
    hipLaunchKernelGGL(prep_w_zero, dim3(49), dim3(256), 0, stream, wqkv, wbf, G);
    // x -> xT bf16
    hipLaunchKernelGGL(transpose_cb, dim3(256, 4, 8), dim3(256), 0, stream, x, xT);
    // K1: qkv1 = Wqkv @ x
    hipLaunchKernelGGL(mfma_gemm_k1, dim3(128, 3, 8), dim3(256), 0, stream,
                       wbf, xT, qkv1);
    // dw(v) + gating -> Vg (overwrites dead xT slot)
    hipLaunchKernelGGL(dw_v_gate, dim3(8, 128, 8), dim3(256), 0, stream,
                       qkv1, wdw, illu, Vg);
    // fused dw(q,k) + norms + gram
    hipLaunchKernelGGL(dw_qk_gram, dim3(16, 8, 8), dim3(256), 0, stream,
                       qkv1, wdw, G, nqk);
    // softmax + compose -> CtBo
    hipLaunchKernelGGL(softmax_compose, dim3(8), dim3(256), 0, stream,
                       G, nqk, temp, wproj, CtBo);
    // K6: out = CtBo @ Vg (in-kernel V transpose)
    hipLaunchKernelGGL(mfma_k6, dim3(128, 8), dim3(256), 0, stream,
                       CtBo, Vg, out);
}